// Round 11
// baseline (189.711 us; speedup 1.0000x reference)
//
#include <hip/hip_runtime.h>
#include <hip/hip_bf16.h>

// Problem constants (fixed by reference)
#define DIMC 1024
#define HEADS 16
#define HEAD_DIM 64
#define KWIN 13
#define NSH 6
#define LSEQ 4096
#define BATCH 2
#define NROWS (BATCH*LSEQ)        // 8192 token rows
#define QKV_N (3*DIMC)            // 3072
#define SCALE_Q 0.125f            // 64^-0.5

#define TBLK 256                  // tokens per natten block
#define WROWS 268                 // staged K/V window rows (256 + 12)

typedef __attribute__((ext_vector_type(4))) float f32x4;
typedef __attribute__((ext_vector_type(8))) short bf16x8;

__device__ __forceinline__ void gload_lds16(const void* g, void* l) {
  __builtin_amdgcn_global_load_lds(
      (const __attribute__((address_space(1))) void*)g,
      (__attribute__((address_space(3))) void*)l, 16, 0, 0);
}

// unpack 8 bf16 (in uint4) -> 8 f32
__device__ __forceinline__ void cvt8(uint4 r, float* f) {
  unsigned u[4] = {r.x, r.y, r.z, r.w};
#pragma unroll
  for (int w = 0; w < 4; w++) {
    f[2*w]   = __uint_as_float(u[w] << 16);
    f[2*w+1] = __uint_as_float(u[w] & 0xffff0000u);
  }
}

// ---------------- fused cast fp32 -> bf16, 8 elems/thread, 16B stores --------
__global__ __launch_bounds__(256) void cast3_kernel(const float* __restrict__ in0, __hip_bfloat16* __restrict__ out0, int n0,
                                                    const float* __restrict__ in1, __hip_bfloat16* __restrict__ out1, int n1,
                                                    const float* __restrict__ in2, __hip_bfloat16* __restrict__ out2, int n2) {
  // n* counted in 8-float groups
  int i = blockIdx.x * 256 + threadIdx.x;
  const float* in; __hip_bfloat16* out; int k;
  if (i < n0) { in = in0; out = out0; k = i; }
  else if (i < n0 + n1) { in = in1; out = out1; k = i - n0; }
  else if (i < n0 + n1 + n2) { in = in2; out = out2; k = i - n0 - n1; }
  else return;
  const float4* p = (const float4*)in + (size_t)k * 2;
  float4 a = p[0], b = p[1];
  union { ushort us[8]; uint4 v; } o;
  __hip_bfloat16 h;
  h = __float2bfloat16(a.x); o.us[0] = *(ushort*)&h;
  h = __float2bfloat16(a.y); o.us[1] = *(ushort*)&h;
  h = __float2bfloat16(a.z); o.us[2] = *(ushort*)&h;
  h = __float2bfloat16(a.w); o.us[3] = *(ushort*)&h;
  h = __float2bfloat16(b.x); o.us[4] = *(ushort*)&h;
  h = __float2bfloat16(b.y); o.us[5] = *(ushort*)&h;
  h = __float2bfloat16(b.z); o.us[6] = *(ushort*)&h;
  h = __float2bfloat16(b.w); o.us[7] = *(ushort*)&h;
  ((uint4*)out)[k] = o.v;
}

// ---------------- bf16 GEMM: C[M][N] = A[M][K] * B[N][K]^T + bias ----------------
// 128x128 tile, BK=32, 256 threads (4 waves, 2x2 grid of 64x64 wave subtiles).
// A: global_load_lds width-16 staging + chunk-XOR swizzle + ds_read_b128 (R5/R9).
// B (R11): streamed global -> REGISTERS (per-lane bf16x8 = exactly the MFMA
// fragment; L2-hot panel). Halves LDS-pipe reads (the measured critical path),
// halves DMA, LDS 32->16KB. B prefetched 1 K-step ahead into a second named
// reg set (unroll-by-2; rule #20 safe). Double-buffered A as in R9.
// Epilogue: R5's direct scattered stores (0 conflicts).

#define STAGEA(s) do { \
  __hip_bfloat16* dst_ = smem + (s) * 4096 + wave * 1024; \
  gload_lds16(gA,       dst_); \
  gload_lds16(gA + r16, dst_ + 512); \
  gA += 32; \
} while (0)

#define LOADB(dst, t) do { \
  const __hip_bfloat16* p_ = gBr + (size_t)(t) * 32; \
  _Pragma("unroll") for (int i = 0; i < 4; i++) \
    dst[i] = *(const bf16x8*)(p_ + (size_t)i * 16 * K); \
} while (0)

#define COMPUTEAB(s, breg) do { \
  const __hip_bfloat16* As_ = smem + (s) * 4096; \
  bf16x8 af[4]; \
  _Pragma("unroll") for (int i = 0; i < 4; i++) \
    af[i] = *(const bf16x8*)&As_[(wr * 64 + i * 16 + fr) * 32 + fk0]; \
  _Pragma("unroll") for (int mi = 0; mi < 4; mi++) \
  _Pragma("unroll") for (int ni = 0; ni < 4; ni++) \
    acc[mi][ni] = __builtin_amdgcn_mfma_f32_16x16x32_bf16(af[mi], breg[ni], acc[mi][ni], 0, 0, 0); \
} while (0)

template<int OUT_BF16>
__global__ __launch_bounds__(256) void gemm_bt(const __hip_bfloat16* __restrict__ A,
                                               const __hip_bfloat16* __restrict__ B,
                                               const float* __restrict__ bias,
                                               void* __restrict__ Cout,
                                               int M, int N, int K, int nbx) {
  // two A buffers of 8KB: set s at element s*4096
  __shared__ __align__(16) __hip_bfloat16 smem[8192];

  const int tid  = threadIdx.x;
  const int lane = tid & 63;
  const int wave = tid >> 6;

  // m204 bijective XCD swizzle on flattened grid
  int id = blockIdx.x;
  {
    const int nwg = gridDim.x;
    const int q = nwg >> 3, r = nwg & 7;
    const int xcd = id & 7, off = id >> 3;
    id = (xcd < r ? xcd * (q + 1) : r * (q + 1) + (xcd - r) * q) + off;
  }
  const int bx = id % nbx;
  const int by = id / nbx;
  const int m0 = by * 128;
  const int n0 = bx * 128;
  const int wr = wave >> 1;
  const int wc = wave & 1;

  f32x4 acc[4][4] = {};

  // A staging: wave covers rows wave*32..+32; LDS chunk (lane&3) <- global
  // chunk (lane&3) ^ perm(row), perm=(row>>1)&3
  const int rA0  = wave * 32 + (lane >> 2);
  const int kcol = ((lane & 3) ^ ((lane >> 3) & 3)) * 8;
  const __hip_bfloat16* gA = A + (size_t)(m0 + rA0) * K + kcol;
  const size_t r16 = (size_t)16 * K;

  // A fragment read: row = base + fr, read LDS chunk (lane>>4) ^ ((fr>>1)&3)
  const int fr  = lane & 15;
  const int fq  = lane >> 4;          // 0..3
  const int fk0 = ((fq ^ ((fr >> 1) & 3)) & 3) * 8;

  // B fragment source (global, per-lane 16B = the exact MFMA fragment):
  // frag i = B[(n0 + wc*64 + i*16 + fr)*K + t*32 + fq*8 .. +8)
  const __hip_bfloat16* gBr = B + (size_t)(n0 + wc * 64 + fr) * K + fq * 8;

  bf16x8 b0[4], b1[4];

  const int NT = K >> 5;              // 32 K-tiles at K=1024 (even)

  // prologue: tile 0 -> A set 0 + b0
  STAGEA(0);
  LOADB(b0, 0);
  __syncthreads();

  int t = 1;
#pragma unroll 1
  for (int i = 0; i < (NT - 2) / 2; i++) {
    STAGEA(1); LOADB(b1, t); COMPUTEAB(0, b0); __syncthreads(); t++;
    STAGEA(0); LOADB(b0, t); COMPUTEAB(1, b1); __syncthreads(); t++;
  }
  // t == NT-1: stage last tile, compute tile NT-2, then last compute
  STAGEA(1); LOADB(b1, t); COMPUTEAB(0, b0); __syncthreads();
  COMPUTEAB(1, b1);

  // epilogue: C/D layout col = lane&15, row = (lane>>4)*4 + reg  (R5 version)
#pragma unroll
  for (int ni = 0; ni < 4; ni++) {
    const int col = n0 + wc * 64 + ni * 16 + (lane & 15);
    const float bv = bias[col];
#pragma unroll
    for (int mi = 0; mi < 4; mi++) {
      const int row = m0 + wr * 64 + mi * 16 + ((lane >> 4) << 2);
#pragma unroll
      for (int i = 0; i < 4; i++) {
        const float v = acc[mi][ni][i] + bv;
        if (OUT_BF16)
          ((__hip_bfloat16*)Cout)[(size_t)(row + i) * N + col] = __float2bfloat16(v);
        else
          ((float*)Cout)[(size_t)(row + i) * N + col] = v;
      }
    }
  }
}

// ---------------- neighborhood attention: lane-per-token ----------------
__global__ __launch_bounds__(256, 2) void natten(const __hip_bfloat16* __restrict__ qkv,
                                                 const float* __restrict__ rpb,
                                                 __hip_bfloat16* __restrict__ att) {
  __shared__ __align__(16) unsigned char smem[2 * WROWS * 128];  // K then V, swizzled

  const int tid = threadIdx.x;
  const int tb  = blockIdx.x;
  const int h   = blockIdx.y;
  const int b   = blockIdx.z;
  const int t0  = tb * TBLK;

  int r0 = t0 - NSH;
  if (r0 < 0) r0 = 0;
  if (r0 > LSEQ - WROWS) r0 = LSEQ - WROWS;

  const __hip_bfloat16* kg = qkv + ((size_t)b * LSEQ + r0) * QKV_N + DIMC + h * HEAD_DIM;
  const __hip_bfloat16* vg = kg + DIMC;
#pragma unroll 1
  for (int i = tid; i < WROWS * 8; i += 256) {
    const int row = i >> 3, c = i & 7;
    const uint4 kk = *(const uint4*)(kg + (size_t)row * QKV_N + c * 8);
    const uint4 vv = *(const uint4*)(vg + (size_t)row * QKV_N + c * 8);
    const int off = row * 128 + ((c * 16) ^ ((row & 7) << 4));
    *(uint4*)(smem + off) = kk;
    *(uint4*)(smem + WROWS * 128 + off) = vv;
  }
  __syncthreads();

  const int t = t0 + tid;
  int ni = t - NSH;
  ni = ni < 0 ? 0 : (ni > LSEQ - KWIN ? LSEQ - KWIN : ni);
  const int rbase = ni - r0;
  const int pi = NSH + (t < NSH ? NSH - t : 0) + (t + NSH >= LSEQ ? LSEQ - t - 1 - NSH : 0);
  const float* rp = rpb + h * (2 * KWIN - 1) + pi;

  const __hip_bfloat16* qg = qkv + ((size_t)b * LSEQ + t) * QKV_N + h * HEAD_DIM;
  float qf[64];
#pragma unroll
  for (int c = 0; c < 8; c++) {
    uint4 qq = *(const uint4*)(qg + c * 8);
    cvt8(qq, qf + c * 8);
  }

  float p[KWIN];
#pragma unroll
  for (int j = 0; j < KWIN; j++) {
    const int row = rbase + j;
    const int sw = (row & 7) << 4;
    float s = 0.f;
#pragma unroll
    for (int c = 0; c < 8; c++) {
      uint4 kk = *(const uint4*)(smem + row * 128 + ((c * 16) ^ sw));
      float kf[8];
      cvt8(kk, kf);
#pragma unroll
      for (int e = 0; e < 8; e++) s += qf[c * 8 + e] * kf[e];
    }
    p[j] = s * SCALE_Q + rp[j];
  }

  float m = p[0];
#pragma unroll
  for (int j = 1; j < KWIN; j++) m = fmaxf(m, p[j]);
  float sum = 0.f;
#pragma unroll
  for (int j = 0; j < KWIN; j++) { p[j] = __expf(p[j] - m); sum += p[j]; }
  const float inv = 1.f / sum;
#pragma unroll
  for (int j = 0; j < KWIN; j++) p[j] *= inv;

  __hip_bfloat16* og = att + ((size_t)b * LSEQ + t) * DIMC + h * HEAD_DIM;
#pragma unroll
  for (int c = 0; c < 8; c++) {
    float acc[8] = {0.f, 0.f, 0.f, 0.f, 0.f, 0.f, 0.f, 0.f};
#pragma unroll
    for (int j = 0; j < KWIN; j++) {
      const int row = rbase + j;
      uint4 vv = *(const uint4*)(smem + WROWS * 128 + row * 128 + ((c * 16) ^ ((row & 7) << 4)));
      float vf[8];
      cvt8(vv, vf);
#pragma unroll
      for (int e = 0; e < 8; e++) acc[e] += p[j] * vf[e];
    }
    union { ushort us[8]; uint4 v; } o;
#pragma unroll
    for (int e = 0; e < 8; e++) {
      __hip_bfloat16 hb = __float2bfloat16(acc[e]);
      o.us[e] = *(ushort*)&hb;
    }
    *(uint4*)(og + c * 8) = o.v;
  }
}

// ---------------- launch ----------------
extern "C" void kernel_launch(void* const* d_in, const int* in_sizes, int n_in,
                              void* d_out, int out_size, void* d_ws, size_t ws_size,
                              hipStream_t stream) {
  const float* x      = (const float*)d_in[0];
  const float* qkv_w  = (const float*)d_in[1];
  const float* qkv_b  = (const float*)d_in[2];
  const float* rpb    = (const float*)d_in[3];
  const float* proj_w = (const float*)d_in[4];
  const float* proj_b = (const float*)d_in[5];
  float* out = (float*)d_out;

  char* ws = (char*)d_ws;
  __hip_bfloat16* xb    = (__hip_bfloat16*)(ws);
  __hip_bfloat16* wqkv  = (__hip_bfloat16*)(ws + 16777216);
  __hip_bfloat16* wproj = (__hip_bfloat16*)(ws + 23068672);
  __hip_bfloat16* qkv   = (__hip_bfloat16*)(ws + 25165824);
  __hip_bfloat16* att   = (__hip_bfloat16*)(ws + 75497472);

  const int n0 = NROWS * DIMC / 8;   // x       (8-float groups)
  const int n1 = QKV_N * DIMC / 8;   // qkv_w
  const int n2 = DIMC * DIMC / 8;    // proj_w
  cast3_kernel<<<(n0 + n1 + n2 + 255) / 256, 256, 0, stream>>>(
      x, xb, n0, qkv_w, wqkv, n1, proj_w, wproj, n2);

  gemm_bt<1><<<(QKV_N / 128) * (NROWS / 128), 256, 0, stream>>>(
      xb, wqkv, qkv_b, (void*)qkv, NROWS, QKV_N, DIMC, QKV_N / 128);

  natten<<<dim3(LSEQ / TBLK, HEADS, BATCH), 256, 0, stream>>>(qkv, rpb, att);

  gemm_bt<0><<<(DIMC / 128) * (NROWS / 128), 256, 0, stream>>>(
      att, wproj, proj_b, (void*)out, NROWS, DIMC, DIMC, DIMC / 128);
}

// Round 12
// 134.426 us; speedup vs baseline: 1.4113x; 1.4113x over previous
//
#include <hip/hip_runtime.h>
#include <hip/hip_bf16.h>

// Problem constants (fixed by reference)
#define DIMC 1024
#define HEADS 16
#define HEAD_DIM 64
#define KWIN 13
#define NSH 6
#define LSEQ 4096
#define BATCH 2
#define NROWS (BATCH*LSEQ)        // 8192 token rows
#define QKV_N (3*DIMC)            // 3072
#define SCALE_Q 0.125f            // 64^-0.5

#define TBLK 256                  // tokens per natten block
#define WROWS 268                 // staged K/V window rows (256 + 12)

typedef __attribute__((ext_vector_type(4))) float f32x4;
typedef __attribute__((ext_vector_type(8))) short bf16x8;

__device__ __forceinline__ void gload_lds16(const void* g, void* l) {
  __builtin_amdgcn_global_load_lds(
      (const __attribute__((address_space(1))) void*)g,
      (__attribute__((address_space(3))) void*)l, 16, 0, 0);
}

// unpack 8 bf16 (in uint4) -> 8 f32
__device__ __forceinline__ void cvt8(uint4 r, float* f) {
  unsigned u[4] = {r.x, r.y, r.z, r.w};
#pragma unroll
  for (int w = 0; w < 4; w++) {
    f[2*w]   = __uint_as_float(u[w] << 16);
    f[2*w+1] = __uint_as_float(u[w] & 0xffff0000u);
  }
}

// ---------------- fused cast fp32 -> bf16, 8 elems/thread, 16B stores --------
__global__ __launch_bounds__(256) void cast3_kernel(const float* __restrict__ in0, __hip_bfloat16* __restrict__ out0, int n0,
                                                    const float* __restrict__ in1, __hip_bfloat16* __restrict__ out1, int n1,
                                                    const float* __restrict__ in2, __hip_bfloat16* __restrict__ out2, int n2) {
  // n* counted in 8-float groups
  int i = blockIdx.x * 256 + threadIdx.x;
  const float* in; __hip_bfloat16* out; int k;
  if (i < n0) { in = in0; out = out0; k = i; }
  else if (i < n0 + n1) { in = in1; out = out1; k = i - n0; }
  else if (i < n0 + n1 + n2) { in = in2; out = out2; k = i - n0 - n1; }
  else return;
  const float4* p = (const float4*)in + (size_t)k * 2;
  float4 a = p[0], b = p[1];
  union { ushort us[8]; uint4 v; } o;
  __hip_bfloat16 h;
  h = __float2bfloat16(a.x); o.us[0] = *(ushort*)&h;
  h = __float2bfloat16(a.y); o.us[1] = *(ushort*)&h;
  h = __float2bfloat16(a.z); o.us[2] = *(ushort*)&h;
  h = __float2bfloat16(a.w); o.us[3] = *(ushort*)&h;
  h = __float2bfloat16(b.x); o.us[4] = *(ushort*)&h;
  h = __float2bfloat16(b.y); o.us[5] = *(ushort*)&h;
  h = __float2bfloat16(b.z); o.us[6] = *(ushort*)&h;
  h = __float2bfloat16(b.w); o.us[7] = *(ushort*)&h;
  ((uint4*)out)[k] = o.v;
}

// ---------------- bf16 GEMM: C[M][N] = A[M][K] * B[N][K]^T + bias ----------------
// 128x128 tile, BK=32, 256 threads (4 waves, 2x2 grid of 64x64 wave subtiles),
// global_load_lds width=16 staging, mfma_f32_16x16x32_bf16.
// LDS chunk-XOR swizzle (perm(row)=(row>>1)&3) on staging+fragment reads (R5).
// R9: double-buffered pipelined 2-phase (prefetch next tile before compute).
// R10: 1-D grid + m204 bijective XCD swizzle (L2 reuse; FETCH 71.7->57.5 MB).
// R11's B-reg streaming REVERTED: per-lane stride-K loads are uncoalesced
// (64 cache lines per instr) -> gemm 73->120 µs. This is the best-known form.
// Epilogue: R5's direct scattered stores (0 conflicts).

#define STAGE4(s) do { \
  __hip_bfloat16* dst_ = smem + (s) * 8192 + wave * 1024; \
  gload_lds16(gA,       dst_); \
  gload_lds16(gA + r16, dst_ + 512); \
  gload_lds16(gB,       dst_ + 4096); \
  gload_lds16(gB + r16, dst_ + 4096 + 512); \
} while (0)

#define COMPUTE16(s) do { \
  const __hip_bfloat16* As_ = smem + (s) * 8192; \
  const __hip_bfloat16* Bs_ = As_ + 4096; \
  bf16x8 af[4], bfr[4]; \
  _Pragma("unroll") for (int i = 0; i < 4; i++) \
    af[i] = *(const bf16x8*)&As_[(wr * 64 + i * 16 + fr) * 32 + fk0]; \
  _Pragma("unroll") for (int i = 0; i < 4; i++) \
    bfr[i] = *(const bf16x8*)&Bs_[(wc * 64 + i * 16 + fr) * 32 + fk0]; \
  _Pragma("unroll") for (int mi = 0; mi < 4; mi++) \
  _Pragma("unroll") for (int ni = 0; ni < 4; ni++) \
    acc[mi][ni] = __builtin_amdgcn_mfma_f32_16x16x32_bf16(af[mi], bfr[ni], acc[mi][ni], 0, 0, 0); \
} while (0)

template<int OUT_BF16>
__global__ __launch_bounds__(256) void gemm_bt(const __hip_bfloat16* __restrict__ A,
                                               const __hip_bfloat16* __restrict__ B,
                                               const float* __restrict__ bias,
                                               void* __restrict__ Cout,
                                               int M, int N, int K, int nbx) {
  // two buffer sets of 16KB: set s at element s*8192 (As 4096 elem | Bs 4096 elem)
  __shared__ __align__(16) __hip_bfloat16 smem[16384];

  const int tid  = threadIdx.x;
  const int lane = tid & 63;
  const int wave = tid >> 6;

  // m204 bijective XCD swizzle on flattened grid
  int id = blockIdx.x;
  {
    const int nwg = gridDim.x;
    const int q = nwg >> 3, r = nwg & 7;
    const int xcd = id & 7, off = id >> 3;
    id = (xcd < r ? xcd * (q + 1) : r * (q + 1) + (xcd - r) * q) + off;
  }
  const int bx = id % nbx;
  const int by = id / nbx;
  const int m0 = by * 128;
  const int n0 = bx * 128;
  const int wr = wave >> 1;
  const int wc = wave & 1;

  f32x4 acc[4][4] = {};

  // staging: call c covers rows wave*32 + c*16 + (lane>>2); 4 lanes/row,
  // LDS chunk (lane&3) <- global chunk (lane&3) ^ perm(row), perm=(row>>1)&3
  const int rA0  = wave * 32 + (lane >> 2);
  const int kcol = ((lane & 3) ^ ((lane >> 3) & 3)) * 8;
  const __hip_bfloat16* gA = A + (size_t)(m0 + rA0) * K + kcol;
  const __hip_bfloat16* gB = B + (size_t)(n0 + rA0) * K + kcol;
  const size_t r16 = (size_t)16 * K;

  // fragment read: row = base + fr, read LDS chunk (lane>>4) ^ ((fr>>1)&3)
  const int fr  = lane & 15;
  const int fq  = lane >> 4;          // 0..3
  const int fk0 = ((fq ^ ((fr >> 1) & 3)) & 3) * 8;

  const int NT = K >> 5;              // 32 K-tiles at K=1024

  // prologue: stage tile 0 into set 0
  STAGE4(0);
  gA += 32; gB += 32;
  __syncthreads();

  int cur = 0;
#pragma unroll 1
  for (int t = 1; t < NT; t++) {
    STAGE4(cur ^ 1);                  // prefetch tile t into other set
    gA += 32; gB += 32;
    COMPUTE16(cur);                   // compute tile t-1
    __syncthreads();                  // drains this wave's DMA + barrier
    cur ^= 1;
  }
  COMPUTE16(cur);                     // last tile

  // epilogue: C/D layout col = lane&15, row = (lane>>4)*4 + reg  (R5 version)
#pragma unroll
  for (int ni = 0; ni < 4; ni++) {
    const int col = n0 + wc * 64 + ni * 16 + (lane & 15);
    const float bv = bias[col];
#pragma unroll
    for (int mi = 0; mi < 4; mi++) {
      const int row = m0 + wr * 64 + mi * 16 + ((lane >> 4) << 2);
#pragma unroll
      for (int i = 0; i < 4; i++) {
        const float v = acc[mi][ni][i] + bv;
        if (OUT_BF16)
          ((__hip_bfloat16*)Cout)[(size_t)(row + i) * N + col] = __float2bfloat16(v);
        else
          ((float*)Cout)[(size_t)(row + i) * N + col] = v;
      }
    }
  }
}

// ---------------- neighborhood attention: lane-per-token ----------------
__global__ __launch_bounds__(256, 2) void natten(const __hip_bfloat16* __restrict__ qkv,
                                                 const float* __restrict__ rpb,
                                                 __hip_bfloat16* __restrict__ att) {
  __shared__ __align__(16) unsigned char smem[2 * WROWS * 128];  // K then V, swizzled

  const int tid = threadIdx.x;
  const int tb  = blockIdx.x;
  const int h   = blockIdx.y;
  const int b   = blockIdx.z;
  const int t0  = tb * TBLK;

  int r0 = t0 - NSH;
  if (r0 < 0) r0 = 0;
  if (r0 > LSEQ - WROWS) r0 = LSEQ - WROWS;

  const __hip_bfloat16* kg = qkv + ((size_t)b * LSEQ + r0) * QKV_N + DIMC + h * HEAD_DIM;
  const __hip_bfloat16* vg = kg + DIMC;
#pragma unroll 1
  for (int i = tid; i < WROWS * 8; i += 256) {
    const int row = i >> 3, c = i & 7;
    const uint4 kk = *(const uint4*)(kg + (size_t)row * QKV_N + c * 8);
    const uint4 vv = *(const uint4*)(vg + (size_t)row * QKV_N + c * 8);
    const int off = row * 128 + ((c * 16) ^ ((row & 7) << 4));
    *(uint4*)(smem + off) = kk;
    *(uint4*)(smem + WROWS * 128 + off) = vv;
  }
  __syncthreads();

  const int t = t0 + tid;
  int ni = t - NSH;
  ni = ni < 0 ? 0 : (ni > LSEQ - KWIN ? LSEQ - KWIN : ni);
  const int rbase = ni - r0;
  const int pi = NSH + (t < NSH ? NSH - t : 0) + (t + NSH >= LSEQ ? LSEQ - t - 1 - NSH : 0);
  const float* rp = rpb + h * (2 * KWIN - 1) + pi;

  const __hip_bfloat16* qg = qkv + ((size_t)b * LSEQ + t) * QKV_N + h * HEAD_DIM;
  float qf[64];
#pragma unroll
  for (int c = 0; c < 8; c++) {
    uint4 qq = *(const uint4*)(qg + c * 8);
    cvt8(qq, qf + c * 8);
  }

  float p[KWIN];
#pragma unroll
  for (int j = 0; j < KWIN; j++) {
    const int row = rbase + j;
    const int sw = (row & 7) << 4;
    float s = 0.f;
#pragma unroll
    for (int c = 0; c < 8; c++) {
      uint4 kk = *(const uint4*)(smem + row * 128 + ((c * 16) ^ sw));
      float kf[8];
      cvt8(kk, kf);
#pragma unroll
      for (int e = 0; e < 8; e++) s += qf[c * 8 + e] * kf[e];
    }
    p[j] = s * SCALE_Q + rp[j];
  }

  float m = p[0];
#pragma unroll
  for (int j = 1; j < KWIN; j++) m = fmaxf(m, p[j]);
  float sum = 0.f;
#pragma unroll
  for (int j = 0; j < KWIN; j++) { p[j] = __expf(p[j] - m); sum += p[j]; }
  const float inv = 1.f / sum;
#pragma unroll
  for (int j = 0; j < KWIN; j++) p[j] *= inv;

  __hip_bfloat16* og = att + ((size_t)b * LSEQ + t) * DIMC + h * HEAD_DIM;
#pragma unroll
  for (int c = 0; c < 8; c++) {
    float acc[8] = {0.f, 0.f, 0.f, 0.f, 0.f, 0.f, 0.f, 0.f};
#pragma unroll
    for (int j = 0; j < KWIN; j++) {
      const int row = rbase + j;
      uint4 vv = *(const uint4*)(smem + WROWS * 128 + row * 128 + ((c * 16) ^ ((row & 7) << 4)));
      float vf[8];
      cvt8(vv, vf);
#pragma unroll
      for (int e = 0; e < 8; e++) acc[e] += p[j] * vf[e];
    }
    union { ushort us[8]; uint4 v; } o;
#pragma unroll
    for (int e = 0; e < 8; e++) {
      __hip_bfloat16 hb = __float2bfloat16(acc[e]);
      o.us[e] = *(ushort*)&hb;
    }
    *(uint4*)(og + c * 8) = o.v;
  }
}

// ---------------- launch ----------------
extern "C" void kernel_launch(void* const* d_in, const int* in_sizes, int n_in,
                              void* d_out, int out_size, void* d_ws, size_t ws_size,
                              hipStream_t stream) {
  const float* x      = (const float*)d_in[0];
  const float* qkv_w  = (const float*)d_in[1];
  const float* qkv_b  = (const float*)d_in[2];
  const float* rpb    = (const float*)d_in[3];
  const float* proj_w = (const float*)d_in[4];
  const float* proj_b = (const float*)d_in[5];
  float* out = (float*)d_out;

  char* ws = (char*)d_ws;
  __hip_bfloat16* xb    = (__hip_bfloat16*)(ws);
  __hip_bfloat16* wqkv  = (__hip_bfloat16*)(ws + 16777216);
  __hip_bfloat16* wproj = (__hip_bfloat16*)(ws + 23068672);
  __hip_bfloat16* qkv   = (__hip_bfloat16*)(ws + 25165824);
  __hip_bfloat16* att   = (__hip_bfloat16*)(ws + 75497472);

  const int n0 = NROWS * DIMC / 8;   // x       (8-float groups)
  const int n1 = QKV_N * DIMC / 8;   // qkv_w
  const int n2 = DIMC * DIMC / 8;    // proj_w
  cast3_kernel<<<(n0 + n1 + n2 + 255) / 256, 256, 0, stream>>>(
      x, xb, n0, qkv_w, wqkv, n1, proj_w, wproj, n2);

  gemm_bt<1><<<(QKV_N / 128) * (NROWS / 128), 256, 0, stream>>>(
      xb, wqkv, qkv_b, (void*)qkv, NROWS, QKV_N, DIMC, QKV_N / 128);

  natten<<<dim3(LSEQ / TBLK, HEADS, BATCH), 256, 0, stream>>>(qkv, rpb, att);

  gemm_bt<0><<<(DIMC / 128) * (NROWS / 128), 256, 0, stream>>>(
      att, wproj, proj_b, (void*)out, NROWS, DIMC, DIMC, DIMC / 128);
}